// Round 9
// baseline (746.274 us; speedup 1.0000x reference)
//
#include <hip/hip_runtime.h>

#define E_N 100000
#define NTOT 84000
#define NDST 234000   // concatenated per-type dst index space

typedef __attribute__((ext_vector_type(8))) short bfrag8;
typedef __attribute__((ext_vector_type(4))) float accf4;

__device__ __forceinline__ void atomAddF(float* p, float v) {
    unsafeAtomicAdd(p, v);
}

__device__ __forceinline__ float lrelu(float v) { return v >= 0.f ? v : 0.2f * v; }

// fp32 -> bf16 round-to-nearest-even, and back
__device__ __forceinline__ unsigned short f2bf(float f) {
    unsigned u = __float_as_uint(f);
    return (unsigned short)((u + 0x7FFFu + ((u >> 16) & 1u)) >> 16);
}
__device__ __forceinline__ float bf2f(unsigned short h) {
    return __uint_as_float(((unsigned)h) << 16);
}

// CSR dst-space bases per edge type t
__constant__ int c_tbase[8] = {0, 1000, 51000, 71000, 121000, 126000, 176000, 184000};

struct EI8 { const int* p[8]; };

// ---------------- weight pre-split: W[K][256] fp32 -> BThi/BTlo[256][K] bf16 ----------
struct BTJob { const float* W; unsigned short* hi; unsigned short* lo; int K; int kshift; };
struct BTBatch { BTJob j[17]; };

__global__ __launch_bounds__(256) void makeBT(BTBatch b)
{
    BTJob jb = b.j[blockIdx.z];
    int idx = blockIdx.x * 256 + threadIdx.x;   // n*K + k
    if (idx >= (jb.K << 8)) return;
    int n = idx >> jb.kshift;
    int k = idx & (jb.K - 1);
    float w = jb.W[(size_t)k * 256 + n];
    unsigned short h = f2bf(w);
    jb.hi[idx] = h;
    jb.lo[idx] = f2bf(w - bf2f(h));
}

// ---------------- MFMA split-bf16 GEMM: C[M x 256] = A[M x K] @ B[K x 256] ------------
// 128x128 tile, 4 waves in 2x2 quadrants, 4x4 MFMA 16x16x32 tiles each.
// acc += Ahi*B1 + Alo*B1 + Ahi*B2 (missing Alo*B2 ~2^-16 relative).
// Block decode: the two column-half blocks of a row-tile are 8 ids apart -> same XCD
// under round-robin dispatch -> second A read served from that XCD's L2.
struct MJob { const float* A; const unsigned short* BThi; const unsigned short* BTlo;
              float* C; unsigned short* Cbf; const float* bias; int M; int K; int relu; };
struct MBatch { MJob j[8]; };

__global__ __launch_bounds__(256, 2) void gemm_mfma(MBatch batch)
{
    const MJob jb = batch.j[blockIdx.z];
    const int bx = blockIdx.x;
    const int rowblk = (bx >> 4) * 8 + (bx & 7);
    const int half = (bx >> 3) & 1;
    const int bm = rowblk * 128;
    if (bm >= jb.M) return;
    const int bn = half * 128;
    const int M = jb.M, K = jb.K;

    __shared__ unsigned short Ah[128 * 40];
    __shared__ unsigned short Al[128 * 40];
    __shared__ unsigned short B1[128 * 40];
    __shared__ unsigned short B2[128 * 40];

    const int tid  = threadIdx.x;
    const int wv   = tid >> 6;
    const int lane = tid & 63;
    const int qr = wv >> 1, qc = wv & 1;
    const int lm = lane & 15;
    const int lq = lane >> 4;

    accf4 acc[4][4] = {};   // [mt][nt]

    for (int k0 = 0; k0 < K; k0 += 32) {
#pragma unroll
        for (int it = 0; it < 4; ++it) {
            int slot = it * 256 + tid;
            int m  = slot >> 3;
            int kq = (slot & 7) << 2;
            float4 v = make_float4(0.f, 0.f, 0.f, 0.f);
            if (bm + m < M) v = *(const float4*)(jb.A + (size_t)(bm + m) * K + k0 + kq);
            int o = m * 40 + kq;
            unsigned short h0 = f2bf(v.x), h1 = f2bf(v.y), h2 = f2bf(v.z), h3 = f2bf(v.w);
            Ah[o + 0] = h0; Ah[o + 1] = h1; Ah[o + 2] = h2; Ah[o + 3] = h3;
            Al[o + 0] = f2bf(v.x - bf2f(h0));
            Al[o + 1] = f2bf(v.y - bf2f(h1));
            Al[o + 2] = f2bf(v.z - bf2f(h2));
            Al[o + 3] = f2bf(v.w - bf2f(h3));
        }
#pragma unroll
        for (int it = 0; it < 2; ++it) {
            int slot = it * 256 + tid;
            int n  = slot >> 2;
            int kq = (slot & 3) << 3;
            size_t go = (size_t)(bn + n) * K + k0 + kq;
            *(uint4*)&B1[n * 40 + kq] = *(const uint4*)(jb.BThi + go);
            *(uint4*)&B2[n * 40 + kq] = *(const uint4*)(jb.BTlo + go);
        }
        __syncthreads();

        bfrag8 ah[4], al[4], b1[4], b2[4];
#pragma unroll
        for (int t = 0; t < 4; ++t) {
            int am  = qr * 64 + t * 16 + lm;
            int bnn = qc * 64 + t * 16 + lm;
            ah[t] = *(const bfrag8*)&Ah[am * 40 + lq * 8];
            al[t] = *(const bfrag8*)&Al[am * 40 + lq * 8];
            b1[t] = *(const bfrag8*)&B1[bnn * 40 + lq * 8];
            b2[t] = *(const bfrag8*)&B2[bnn * 40 + lq * 8];
        }
#pragma unroll
        for (int mt = 0; mt < 4; ++mt)
#pragma unroll
            for (int nt = 0; nt < 4; ++nt) {
                acc[mt][nt] = __builtin_amdgcn_mfma_f32_16x16x32_bf16(ah[mt], b1[nt], acc[mt][nt], 0, 0, 0);
                acc[mt][nt] = __builtin_amdgcn_mfma_f32_16x16x32_bf16(al[mt], b1[nt], acc[mt][nt], 0, 0, 0);
                acc[mt][nt] = __builtin_amdgcn_mfma_f32_16x16x32_bf16(ah[mt], b2[nt], acc[mt][nt], 0, 0, 0);
            }
        __syncthreads();
    }

#pragma unroll
    for (int nt = 0; nt < 4; ++nt) {
        int col = bn + qc * 64 + nt * 16 + lm;
        float bv = jb.bias ? jb.bias[col] : 0.f;
#pragma unroll
        for (int mt = 0; mt < 4; ++mt) {
            int row0 = bm + qr * 64 + mt * 16 + lq * 4;
#pragma unroll
            for (int r = 0; r < 4; ++r) {
                int row = row0 + r;
                if (row < M) {
                    float o = acc[mt][nt][r] + bv;
                    if (jb.relu) o = fmaxf(o, 0.f);
                    if (jb.C)   jb.C[(size_t)row * 256 + col] = o;
                    if (jb.Cbf) jb.Cbf[(size_t)row * 256 + col] = f2bf(o);
                }
            }
        }
    }
}

// ---------------- effective attention-projection matrices ----------------
// weff layout: [l(2)][nt(5)][k(256)][col(32)]
__global__ __launch_bounds__(256) void fill_weff(const float* __restrict__ Wsrc,
                                                 const float* __restrict__ Wdst,
                                                 const float* __restrict__ asrc,
                                                 const float* __restrict__ adst,
                                                 float* __restrict__ weff)
{
    int idx = blockIdx.x * 256 + threadIdx.x;
    if (idx >= 81920) return;
    int col = idx & 31;
    int k   = (idx >> 5) & 255;
    int lnt = idx >> 13;
    int nt  = lnt % 5;
    int l   = lnt / 5;
    bool is_src; int t, h;
    if (nt == 0) {
        if (col < 16) { is_src = true;  t = (col >> 2) * 2;            h = col & 3; }
        else          { is_src = false; t = ((col - 16) >> 2) * 2 + 1; h = col & 3; }
    } else {
        if (col < 4)      { is_src = true;  t = 2 * nt - 1; h = col; }
        else if (col < 8) { is_src = false; t = 2 * nt - 2; h = col - 4; }
        else { weff[idx] = 0.f; return; }
    }
    const float* W = (is_src ? Wsrc : Wdst) + ((size_t)((l * 8 + t) * 256 + k)) * 256 + h * 64;
    const float* a = (is_src ? asrc : adst) + ((size_t)((l * 8 + t) * 4 + h)) * 64;
    float val = 0.f;
    for (int c = 0; c < 64; c++) val += W[c] * a[c];
    weff[idx] = val;
}

// ---------------- fold projections through L1 attn: effT=Wp_ts@weff0, effC=Wp_c@weffc -
__global__ __launch_bounds__(256) void fillEff(const float* __restrict__ Wp_ts,
                                               const float* __restrict__ bp_ts,
                                               const float* __restrict__ Wp_c,
                                               const float* __restrict__ bp_c,
                                               const float* __restrict__ weff,  // l=0 block
                                               float* __restrict__ effT,        // [64][32]
                                               float* __restrict__ biasT,       // [32]
                                               float* __restrict__ effC,        // [4][128][8]
                                               float* __restrict__ biasC)       // [4][8]
{
    int idx = blockIdx.x * 256 + threadIdx.x;
    if (idx < 2048) {
        int kk = idx >> 5, j = idx & 31;
        float s = 0.f;
        for (int k = 0; k < 256; k++) s += Wp_ts[kk * 256 + k] * weff[k * 32 + j];
        effT[idx] = s;
    } else if (idx < 2080) {
        int j = idx - 2048;
        float s = 0.f;
        for (int k = 0; k < 256; k++) s += bp_ts[k] * weff[k * 32 + j];
        biasT[j] = s;
    } else if (idx < 2080 + 4 * 1032) {
        int r = idx - 2080;
        int q = r / 1032; r -= q * 1032;
        const float* wq = weff + (q + 1) * 8192;
        if (r < 1024) {
            int kk = r >> 3, j = r & 7;
            float s = 0.f;
            for (int k = 0; k < 256; k++) s += Wp_c[(size_t)q * 32768 + kk * 256 + k] * wq[k * 32 + j];
            effC[(q * 128 + kk) * 8 + j] = s;
        } else {
            int j = r - 1024;
            float s = 0.f;
            for (int k = 0; k < 256; k++) s += bp_c[q * 256 + k] * wq[k * 32 + j];
            biasC[q * 8 + j] = s;
        }
    }
}

// attnT_L1 = ts_x @ effT + biasT
__global__ __launch_bounds__(256) void attnprojA(const float* __restrict__ ts_x,
                                                 const float* __restrict__ effT,
                                                 const float* __restrict__ biasT,
                                                 float* __restrict__ attnT)
{
    int n = blockIdx.x * 256 + threadIdx.x;
    if (n >= 50000) return;
    float acc[32];
#pragma unroll
    for (int j = 0; j < 32; j++) acc[j] = biasT[j];
    const float* xr = ts_x + (size_t)n * 64;
    for (int k = 0; k < 64; k += 4) {
        float4 xv = *(const float4*)(xr + k);
#pragma unroll
        for (int j = 0; j < 32; j++)
            acc[j] += xv.x * effT[(k + 0) * 32 + j] + xv.y * effT[(k + 1) * 32 + j]
                    + xv.z * effT[(k + 2) * 32 + j] + xv.w * effT[(k + 3) * 32 + j];
    }
#pragma unroll
    for (int j = 0; j < 32; j++) attnT[(size_t)n * 32 + j] = acc[j];
}

// attnC_L1 = emb @ effC + biasC
__global__ __launch_bounds__(256) void attnprojC1(const float* __restrict__ e0,
                                                  const float* __restrict__ e1,
                                                  const float* __restrict__ e2,
                                                  const float* __restrict__ e3,
                                                  const float* __restrict__ effC,
                                                  const float* __restrict__ biasC,
                                                  float* __restrict__ attnC)
{
    int m = blockIdx.x * 256 + threadIdx.x;
    if (m >= 34000) return;
    int q, loc;
    if (m < 1000)       { q = 0; loc = m; }
    else if (m < 21000) { q = 1; loc = m - 1000; }
    else if (m < 26000) { q = 2; loc = m - 21000; }
    else                { q = 3; loc = m - 26000; }
    const float* er = (q == 0 ? e0 : q == 1 ? e1 : q == 2 ? e2 : e3) + (size_t)loc * 128;
    const float* W = effC + q * 1024;
    float acc[8];
#pragma unroll
    for (int j = 0; j < 8; j++) acc[j] = biasC[q * 8 + j];
    for (int k = 0; k < 128; k += 4) {
        float4 xv = *(const float4*)(er + k);
#pragma unroll
        for (int j = 0; j < 8; j++)
            acc[j] += xv.x * W[(k + 0) * 8 + j] + xv.y * W[(k + 1) * 8 + j]
                    + xv.z * W[(k + 2) * 8 + j] + xv.w * W[(k + 3) * 8 + j];
    }
#pragma unroll
    for (int j = 0; j < 8; j++) attnC[(size_t)m * 8 + j] = acc[j];
}

// attnC_L2 from materialized x1 compact rows (full 256-dot, weff_l2)
template<int NO>
__device__ __forceinline__ void attnproj_body(const float* __restrict__ xrow,
                                              const float* __restrict__ W,
                                              float* __restrict__ out)
{
    float acc[NO];
#pragma unroll
    for (int j = 0; j < NO; j++) acc[j] = 0.f;
    for (int k = 0; k < 256; k += 4) {
        const float4 xv = *(const float4*)(xrow + k);
#pragma unroll
        for (int j = 0; j < NO; j++) {
            acc[j] += xv.x * W[(k + 0) * 32 + j] + xv.y * W[(k + 1) * 32 + j]
                    + xv.z * W[(k + 2) * 32 + j] + xv.w * W[(k + 3) * 32 + j];
        }
    }
#pragma unroll
    for (int j = 0; j < NO; j++) out[j] = acc[j];
}

__global__ __launch_bounds__(256) void attnprojC2(const float* __restrict__ x1,
                                                  const float* __restrict__ weff_l,
                                                  float* __restrict__ attnC)
{
    int m = blockIdx.x * 256 + threadIdx.x;
    if (m >= 34000) return;
    int n = 50000 + m;
    int nt = (n < 51000) ? 1 : (n < 71000) ? 2 : (n < 76000) ? 3 : 4;
    attnproj_body<8>(x1 + (size_t)n * 256, weff_l + nt * 8192, attnC + (size_t)m * 8);
}

// ---------------- CSR build ----------------
__global__ __launch_bounds__(256) void count_k(EI8 ei, int* __restrict__ cnt)
{
    int g = blockIdx.x * 256 + threadIdx.x;
    if (g >= 8 * E_N) return;
    int t = g / E_N;
    int i = g - t * E_N;
    int d = ei.p[t][E_N + i];
    atomicAdd(&cnt[c_tbase[t] + d], 1);
}

__global__ __launch_bounds__(256) void scanA(const int* __restrict__ cnt,
                                             int* __restrict__ rowptr,
                                             int* __restrict__ bsum)
{
    __shared__ int sd[256];
    int b = blockIdx.x, t = threadIdx.x;
    int base = b * 1024 + t * 4;
    int v0 = 0, v1 = 0, v2 = 0, v3 = 0;
    if (base + 0 < NDST) v0 = cnt[base + 0];
    if (base + 1 < NDST) v1 = cnt[base + 1];
    if (base + 2 < NDST) v2 = cnt[base + 2];
    if (base + 3 < NDST) v3 = cnt[base + 3];
    int s = v0 + v1 + v2 + v3;
    sd[t] = s;
    __syncthreads();
    for (int off = 1; off < 256; off <<= 1) {
        int x = 0;
        if (t >= off) x = sd[t - off];
        __syncthreads();
        if (t >= off) sd[t] += x;
        __syncthreads();
    }
    int run = sd[t] - s;
    if (t == 255) bsum[b] = sd[255];
    if (base + 0 < NDST) rowptr[base + 0] = run;          run += v0;
    if (base + 1 < NDST) rowptr[base + 1] = run;          run += v1;
    if (base + 2 < NDST) rowptr[base + 2] = run;          run += v2;
    if (base + 3 < NDST) rowptr[base + 3] = run;
}

__global__ __launch_bounds__(256) void scanB(int* __restrict__ bsum, int nb)
{
    __shared__ int sd[256];
    int t = threadIdx.x;
    int v = (t < nb) ? bsum[t] : 0;
    sd[t] = v;
    __syncthreads();
    for (int off = 1; off < 256; off <<= 1) {
        int x = 0;
        if (t >= off) x = sd[t - off];
        __syncthreads();
        if (t >= off) sd[t] += x;
        __syncthreads();
    }
    if (t < nb) bsum[t] = sd[t] - v;
}

__global__ __launch_bounds__(256) void scanC(int* __restrict__ rowptr,
                                             const int* __restrict__ bsum,
                                             int* __restrict__ cursor)
{
    int b = blockIdx.x, t = threadIdx.x;
    int off = bsum[b];
    int base = b * 1024 + t * 4;
#pragma unroll
    for (int j = 0; j < 4; j++) {
        int i = base + j;
        if (i < NDST) {
            int r = rowptr[i] + off;
            rowptr[i] = r;
            cursor[i] = r;
        }
    }
    if (b == 0 && t == 0) rowptr[NDST] = 8 * E_N;
}

__global__ __launch_bounds__(256) void place_k(EI8 ei, int* __restrict__ cursor,
                                               int* __restrict__ ssrc)
{
    int g = blockIdx.x * 256 + threadIdx.x;
    if (g >= 8 * E_N) return;
    int t = g / E_N;
    int i = g - t * E_N;
    int d = ei.p[t][E_N + i];
    int s = ei.p[t][i];
    int pos = atomicAdd(&cursor[c_tbase[t] + d], 1);
    ssrc[pos] = s;
}

// ---------------- aggregate-first ts->compact: bf16 gather, unroll-4 -----------------
__global__ __launch_bounds__(256) void aggx_k(const float* __restrict__ attnT,
                                              const float* __restrict__ attnC,
                                              const unsigned short* __restrict__ xtsbf,
                                              const int* __restrict__ rowptr,
                                              const int* __restrict__ ssrc,
                                              float* __restrict__ aggx)
{
    int w = blockIdx.x * 4 + (threadIdx.x >> 6);   // 0..33999 (grid 8500)
    int lane = threadIdx.x & 63;
    int h = lane >> 4;
    int ch = (h << 6) | ((lane & 15) << 2);
    int q, dloc;
    if (w < 1000)       { q = 0; dloc = w; }
    else if (w < 21000) { q = 1; dloc = w - 1000; }
    else if (w < 26000) { q = 2; dloc = w - 21000; }
    else                { q = 3; dloc = w - 26000; }
    const int csr4[4]  = {0, 51000, 121000, 176000};
    const int soff4[4] = {0, 4, 8, 12};
    int soff = soff4[q];
    int r0 = rowptr[csr4[q] + dloc], r1 = rowptr[csr4[q] + dloc + 1];
    float ed = attnC[(size_t)w * 8 + 4 + h];
    float den = 0.f, sx = 0.f, sy = 0.f, sz = 0.f, sw = 0.f;
    int e = r0;
    for (; e + 4 <= r1; e += 4) {
        int sA = ssrc[e], sB = ssrc[e + 1], sC = ssrc[e + 2], sD = ssrc[e + 3];
        float eA = attnT[(size_t)sA * 32 + soff + h];
        float eB = attnT[(size_t)sB * 32 + soff + h];
        float eC = attnT[(size_t)sC * 32 + soff + h];
        float eD = attnT[(size_t)sD * 32 + soff + h];
        ushort4 rA = *(const ushort4*)(xtsbf + (size_t)sA * 256 + ch);
        ushort4 rB = *(const ushort4*)(xtsbf + (size_t)sB * 256 + ch);
        ushort4 rC = *(const ushort4*)(xtsbf + (size_t)sC * 256 + ch);
        ushort4 rD = *(const ushort4*)(xtsbf + (size_t)sD * 256 + ch);
        float xA = __expf(lrelu(eA + ed));
        float xB = __expf(lrelu(eB + ed));
        float xC = __expf(lrelu(eC + ed));
        float xD = __expf(lrelu(eD + ed));
        den += (xA + xB) + (xC + xD);
        sx += xA * bf2f(rA.x) + xB * bf2f(rB.x) + xC * bf2f(rC.x) + xD * bf2f(rD.x);
        sy += xA * bf2f(rA.y) + xB * bf2f(rB.y) + xC * bf2f(rC.y) + xD * bf2f(rD.y);
        sz += xA * bf2f(rA.z) + xB * bf2f(rB.z) + xC * bf2f(rC.z) + xD * bf2f(rD.z);
        sw += xA * bf2f(rA.w) + xB * bf2f(rB.w) + xC * bf2f(rC.w) + xD * bf2f(rD.w);
    }
    for (; e < r1; e++) {
        int s = ssrc[e];
        float es = attnT[(size_t)s * 32 + soff + h];
        float ex = __expf(lrelu(es + ed));
        den += ex;
        ushort4 rv = *(const ushort4*)(xtsbf + (size_t)s * 256 + ch);
        sx += ex * bf2f(rv.x); sy += ex * bf2f(rv.y);
        sz += ex * bf2f(rv.z); sw += ex * bf2f(rv.w);
    }
    float inv = 1.f / (den + 1e-16f);
    float4 o; o.x = sx * inv; o.y = sy * inv; o.z = sz * inv; o.w = sw * inv;
    *(float4*)(aggx + (size_t)w * 256 + ch) = o;
}

// ---------------- fused compact->ts aggregation core ----------------
__device__ __forceinline__ float4 agg_ts_core(const float* __restrict__ attnT,
                                              const float* __restrict__ attnC,
                                              const unsigned short* __restrict__ hscbf,
                                              const int* __restrict__ rowptr,
                                              const int* __restrict__ ssrc,
                                              const float* __restrict__ bconv_l,
                                              int d, int h, int ch)
{
    const int co4[4]   = {0, 1000, 21000, 26000};
    const int tb4[4]   = {1000, 71000, 126000, 184000};
    const int doff4[4] = {16, 20, 24, 28};
    const int bo4[4]   = {256, 768, 1280, 1792};
    int r0q[4], nq[4]; float edq[4];
    int mx = 0;
#pragma unroll
    for (int q = 0; q < 4; q++) {
        int a = rowptr[tb4[q] + d], b = rowptr[tb4[q] + d + 1];
        r0q[q] = a; nq[q] = b - a;
        mx = max(mx, b - a);
        edq[q] = attnT[(size_t)d * 32 + doff4[q] + h];
    }
    float den[4] = {0.f, 0.f, 0.f, 0.f};
    float sx[4] = {0.f, 0.f, 0.f, 0.f}, sy[4] = {0.f, 0.f, 0.f, 0.f};
    float sz[4] = {0.f, 0.f, 0.f, 0.f}, sw[4] = {0.f, 0.f, 0.f, 0.f};
    for (int i = 0; i < mx; i++) {
#pragma unroll
        for (int q = 0; q < 4; q++) {
            if (i < nq[q]) {
                int s = ssrc[r0q[q] + i];
                float es = attnC[(size_t)(co4[q] + s) * 8 + h];
                float ex = __expf(lrelu(es + edq[q]));
                den[q] += ex;
                ushort4 hv = *(const ushort4*)(hscbf + (size_t)(co4[q] + s) * 256 + ch);
                sx[q] += ex * bf2f(hv.x); sy[q] += ex * bf2f(hv.y);
                sz[q] += ex * bf2f(hv.z); sw[q] += ex * bf2f(hv.w);
            }
        }
    }
    float ax = 0.f, ay = 0.f, az = 0.f, aw = 0.f;
#pragma unroll
    for (int q = 0; q < 4; q++) {
        const float* b = bconv_l + bo4[q] + ch;
        float inv = 1.f / (den[q] + 1e-16f);
        ax += b[0] + sx[q] * inv; ay += b[1] + sy[q] * inv;
        az += b[2] + sz[q] * inv; aw += b[3] + sw[q] * inv;
    }
    float4 o;
    o.x = fmaxf(ax, 0.f); o.y = fmaxf(ay, 0.f);
    o.z = fmaxf(az, 0.f); o.w = fmaxf(aw, 0.f);
    return o;
}

// L1: compute row, fold attnT_L2 (cols 16..31) in-place; x1 ts rows never materialized
__global__ __launch_bounds__(256) void agg_ts_fold(float* __restrict__ attnT,   // in(L1)/out(L2)
                                                   const float* __restrict__ attnC,
                                                   const unsigned short* __restrict__ hscbf,
                                                   const int* __restrict__ rowptr,
                                                   const int* __restrict__ ssrc,
                                                   const float* __restrict__ bconv_l,
                                                   const float* __restrict__ weff2)  // l=1,nt=0 [256][32]
{
    int wv = threadIdx.x >> 6;
    int d = blockIdx.x * 4 + wv;                  // grid 12500
    int lane = threadIdx.x & 63;
    int h = lane >> 4;
    int ch = (h << 6) | ((lane & 15) << 2);
    float4 o = agg_ts_core(attnT, attnC, hscbf, rowptr, ssrc, bconv_l, d, h, ch);
    __shared__ float rowbuf[4][256];
    rowbuf[wv][ch + 0] = o.x; rowbuf[wv][ch + 1] = o.y;
    rowbuf[wv][ch + 2] = o.z; rowbuf[wv][ch + 3] = o.w;
    __syncthreads();
    if (lane < 16) {
        int j = 16 + lane;
        const float* rb = rowbuf[wv];
        float s = 0.f;
        for (int c = 0; c < 256; c++) s += rb[c] * weff2[c * 32 + j];
        attnT[(size_t)d * 32 + j] = s;
    }
}

// L2: block-reduce 4 node rows -> one 256-float partial per block (no x write)
__global__ __launch_bounds__(256) void agg_ts_pool(const float* __restrict__ attnT,
                                                   const float* __restrict__ attnC,
                                                   const unsigned short* __restrict__ hscbf,
                                                   const int* __restrict__ rowptr,
                                                   const int* __restrict__ ssrc,
                                                   const float* __restrict__ bconv_l,
                                                   float* __restrict__ part)
{
    int d = blockIdx.x * 4 + (threadIdx.x >> 6);   // grid 12500
    int lane = threadIdx.x & 63;
    int h = lane >> 4;
    int ch = (h << 6) | ((lane & 15) << 2);
    float4 o = agg_ts_core(attnT, attnC, hscbf, rowptr, ssrc, bconv_l, d, h, ch);
    __shared__ float4 red4[256];
    red4[threadIdx.x] = o;
    __syncthreads();
    if (threadIdx.x < 64) {
        float4 a = red4[threadIdx.x], b = red4[threadIdx.x + 64];
        float4 c = red4[threadIdx.x + 128], dd = red4[threadIdx.x + 192];
        float4 s;
        s.x = (a.x + b.x) + (c.x + dd.x);
        s.y = (a.y + b.y) + (c.y + dd.y);
        s.z = (a.z + b.z) + (c.z + dd.z);
        s.w = (a.w + b.w) + (c.w + dd.w);
        int cch = ((threadIdx.x >> 4) << 6) | ((threadIdx.x & 15) << 2);
        *(float4*)(part + (size_t)blockIdx.x * 256 + cch) = s;
    }
}

// reduce partials: gsum[c] = sum over 12500 block rows
__global__ __launch_bounds__(256) void colsum_part(const float* __restrict__ part,
                                                   float* __restrict__ gsum)
{
    int c = threadIdx.x;
    float s = 0.f;
    for (int r = blockIdx.x; r < 12500; r += gridDim.x) s += part[(size_t)r * 256 + c];
    atomAddF(gsum + c, s);
}

// ---------------- head ----------------
__global__ __launch_bounds__(128) void head_k(const float* __restrict__ gsum,
                                              const float* __restrict__ Wc1,
                                              const float* __restrict__ bc1,
                                              const float* __restrict__ Wc2,
                                              const float* __restrict__ bc2,
                                              float* __restrict__ out)
{
    __shared__ float g[256];
    __shared__ float red[128];
    int t = threadIdx.x;
    g[t] = gsum[t] * (1.f / 50000.f);
    g[t + 128] = gsum[t + 128] * (1.f / 50000.f);
    __syncthreads();
    float acc = bc1[t];
    for (int k = 0; k < 256; k++) acc += g[k] * Wc1[k * 128 + t];
    red[t] = fmaxf(acc, 0.f) * Wc2[t];
    __syncthreads();
    for (int sft = 64; sft > 0; sft >>= 1) {
        if (t < sft) red[t] += red[t + sft];
        __syncthreads();
    }
    if (t == 0) out[0] = red[0] + bc2[0];
}

extern "C" void kernel_launch(void* const* d_in, const int* in_sizes, int n_in,
                              void* d_out, int out_size, void* d_ws, size_t ws_size,
                              hipStream_t stream)
{
    const float* ts_x   = (const float*)d_in[0];
    const float* emb[4] = {(const float*)d_in[1], (const float*)d_in[2],
                           (const float*)d_in[3], (const float*)d_in[4]};
    const float* Wp_ts  = (const float*)d_in[5];
    const float* bp_ts  = (const float*)d_in[6];
    const float* Wp_c   = (const float*)d_in[7];
    const float* bp_c   = (const float*)d_in[8];
    const float* Wsrc   = (const float*)d_in[9];
    const float* Wdst   = (const float*)d_in[10];
    const float* asrc   = (const float*)d_in[11];
    const float* adst   = (const float*)d_in[12];
    const float* bconv  = (const float*)d_in[13];
    const float* Wc1    = (const float*)d_in[14];
    const float* bc1    = (const float*)d_in[15];
    const float* Wc2    = (const float*)d_in[16];
    const float* bc2    = (const float*)d_in[17];
    EI8 ei;
    for (int t = 0; t < 8; t++) ei.p[t] = (const int*)d_in[18 + t];

    // workspace layout (float units)
    float* x0    = (float*)d_ws;           // 21,504,000 (only compact region used)
    float* x1    = x0    + 21504000;       // 21,504,000 (ts region = aggx; compact region = L2 input)
    float* attnT = x1    + 21504000;       // 1,600,000
    float* attnC = attnT + 1600000;        // 272,000
    float* weff  = attnC + 272000;         // 81,920
    float* gsum  = weff  + 81920;          // 256
    float* effT  = gsum  + 256;            // 2,048
    float* biasT = effT  + 2048;           // 32
    float* effC  = biasT + 32;             // 4,096
    float* biasC = effC  + 4096;           // 32
    int* rowptr  = (int*)(biasC + 32);     // 234,004
    int* bsum    = rowptr + 234004;        // 256
    int* ssrc    = bsum + 256;             // 800,000
    unsigned short* xtsbf = (unsigned short*)(ssrc + 800000);   // 12,800,000 us
    unsigned short* hscbf = xtsbf + 12800000;                   //  8,704,000 us
    unsigned short* btp   = hscbf + 8704000;                    //  1,867,776 us
    int* cursor  = (int*)hscbf;            // alias: CSR build finishes before hscbf used
    float* aggx  = x1;                     // alias ts region of x1 (rows 0..33999)
    float* part  = x0;                     // alias: x0 ts region unused; compact reads done before pool

    unsigned short* bt_ts_h = btp;
    unsigned short* bt_ts_l = bt_ts_h + 16384;
    unsigned short* bt_c_h[4], *bt_c_l[4];
    {
        unsigned short* p = bt_ts_l + 16384;
        for (int q = 0; q < 4; q++) { bt_c_h[q] = p; p += 32768; bt_c_l[q] = p; p += 32768; }
    }
    unsigned short* bt_w = bt_ts_l + 16384 + 8 * 32768;
    auto wpan_h = [&](int l, int t) { return bt_w + (size_t)((l == 0 ? t : 8 + t / 2) * 2) * 65536; };
    auto wpan_l = [&](int l, int t) { return wpan_h(l, t) + 65536; };

    // ---- CSR build ----
    hipMemsetAsync(cursor, 0, NDST * sizeof(int), stream);
    count_k<<<3125, 256, 0, stream>>>(ei, cursor);
    scanA<<<229, 256, 0, stream>>>(cursor, rowptr, bsum);
    scanB<<<1, 256, 0, stream>>>(bsum, 229);
    scanC<<<229, 256, 0, stream>>>(rowptr, bsum, cursor);
    place_k<<<3125, 256, 0, stream>>>(ei, cursor, ssrc);

    // ---- weight pre-split ----
    {
        BTBatch b = {};
        int zi = 0;
        b.j[zi++] = {Wp_ts, bt_ts_h, bt_ts_l, 64, 6};
        for (int q = 0; q < 4; q++)
            b.j[zi++] = {Wp_c + q * 32768, bt_c_h[q], bt_c_l[q], 128, 7};
        for (int t = 0; t < 8; t++)
            b.j[zi++] = {Wsrc + (size_t)(0 * 8 + t) * 65536, wpan_h(0, t), wpan_l(0, t), 256, 8};
        for (int t = 1; t < 8; t += 2)
            b.j[zi++] = {Wsrc + (size_t)(1 * 8 + t) * 65536, wpan_h(1, t), wpan_l(1, t), 256, 8};
        makeBT<<<dim3(256, 1, 17), 256, 0, stream>>>(b);
    }

    fill_weff<<<320, 256, 0, stream>>>(Wsrc, Wdst, asrc, adst, weff);
    fillEff<<<25, 256, 0, stream>>>(Wp_ts, bp_ts, Wp_c, bp_c, weff, effT, biasT, effC, biasC);

    // ---- L1 attn logits directly from inputs (folded) ----
    attnprojA<<<196, 256, 0, stream>>>(ts_x, effT, biasT, attnT);
    attnprojC1<<<133, 256, 0, stream>>>(emb[0], emb[1], emb[2], emb[3], effC, biasC, attnC);

    static const int Nd4[4]    = {1000, 20000, 5000, 8000};
    static const int co4[4]    = {0, 1000, 21000, 26000};
    static const int dbase4[4] = {50000, 51000, 71000, 76000};
    static const int tsrc[4]   = {1, 3, 5, 7};
    static const int tdst[4]   = {0, 2, 4, 6};

    // ---- input projections: ts -> bf16 shadow only; compact -> x0 fp32 ----
    {
        MBatch b = {};
        b.j[0] = {ts_x, bt_ts_h, bt_ts_l, nullptr, xtsbf, bp_ts, 50000, 64, 0};
        for (int q = 0; q < 4; q++)
            b.j[1 + q] = {emb[q], bt_c_h[q], bt_c_l[q], x0 + (size_t)dbase4[q] * 256,
                          nullptr, bp_c + q * 256, Nd4[q], 128, 0};
        gemm_mfma<<<dim3(784, 1, 5), 256, 0, stream>>>(b);
    }

    // ---- layer 1 ----
    aggx_k<<<8500, 256, 0, stream>>>(attnT, attnC, xtsbf, rowptr, ssrc, aggx);
    {
        MBatch b = {};
        for (int q = 0; q < 4; q++)
            b.j[q] = {x0 + (size_t)dbase4[q] * 256, wpan_h(0, tsrc[q]), wpan_l(0, tsrc[q]),
                      nullptr, hscbf + (size_t)co4[q] * 256, nullptr, Nd4[q], 256, 0};
        for (int q = 0; q < 4; q++)
            b.j[4 + q] = {aggx + (size_t)co4[q] * 256, wpan_h(0, tdst[q]), wpan_l(0, tdst[q]),
                          x1 + (size_t)dbase4[q] * 256, nullptr, bconv + tdst[q] * 256, Nd4[q], 256, 1};
        gemm_mfma<<<dim3(320, 1, 8), 256, 0, stream>>>(b);
    }
    // L1 aggregation + fold attnT_L2 (in-place); x1 ts rows never written
    agg_ts_fold<<<12500, 256, 0, stream>>>(attnT, attnC, hscbf, rowptr, ssrc, bconv, weff + 40960);

    // ---- layer 2 ----
    attnprojC2<<<133, 256, 0, stream>>>(x1, weff + 40960, attnC);
    {
        MBatch b = {};
        for (int q = 0; q < 4; q++)
            b.j[q] = {x1 + (size_t)dbase4[q] * 256, wpan_h(1, tsrc[q]), wpan_l(1, tsrc[q]),
                      nullptr, hscbf + (size_t)co4[q] * 256, nullptr, Nd4[q], 256, 0};
        gemm_mfma<<<dim3(320, 1, 4), 256, 0, stream>>>(b);
    }
    agg_ts_pool<<<12500, 256, 0, stream>>>(attnT, attnC, hscbf, rowptr, ssrc, bconv + 2048, part);
    hipMemsetAsync(gsum, 0, 256 * sizeof(float), stream);
    colsum_part<<<256, 256, 0, stream>>>(part, gsum);

    head_k<<<1, 128, 0, stream>>>(gsum, Wc1, bc1, Wc2, bc2, (float*)d_out);
}

// Round 10
// 674.641 us; speedup vs baseline: 1.1062x; 1.1062x over previous
//
#include <hip/hip_runtime.h>

#define E_N 100000
#define NTOT 84000
#define NDST 234000   // concatenated per-type dst index space

typedef __attribute__((ext_vector_type(8))) short bfrag8;
typedef __attribute__((ext_vector_type(4))) float accf4;

__device__ __forceinline__ void atomAddF(float* p, float v) {
    unsafeAtomicAdd(p, v);
}

__device__ __forceinline__ float lrelu(float v) { return v >= 0.f ? v : 0.2f * v; }

// fp32 -> bf16 round-to-nearest-even, and back
__device__ __forceinline__ unsigned short f2bf(float f) {
    unsigned u = __float_as_uint(f);
    return (unsigned short)((u + 0x7FFFu + ((u >> 16) & 1u)) >> 16);
}
__device__ __forceinline__ float bf2f(unsigned short h) {
    return __uint_as_float(((unsigned)h) << 16);
}

// CSR dst-space bases per edge type t
__constant__ int c_tbase[8] = {0, 1000, 51000, 71000, 121000, 126000, 176000, 184000};

struct EI8 { const int* p[8]; };

// ---------------- weight pre-split: W[K][256] fp32 -> BThi/BTlo[256][K] bf16 ----------
struct BTJob { const float* W; unsigned short* hi; unsigned short* lo; int K; int kshift; };
struct BTBatch { BTJob j[17]; };

__global__ __launch_bounds__(256) void makeBT(BTBatch b)
{
    BTJob jb = b.j[blockIdx.z];
    int idx = blockIdx.x * 256 + threadIdx.x;   // n*K + k
    if (idx >= (jb.K << 8)) return;
    int n = idx >> jb.kshift;
    int k = idx & (jb.K - 1);
    float w = jb.W[(size_t)k * 256 + n];
    unsigned short h = f2bf(w);
    jb.hi[idx] = h;
    jb.lo[idx] = f2bf(w - bf2f(h));
}

// ---------------- MFMA split-bf16 GEMM: C[M x 256] = A[M x K] @ B[K x 256] ------------
// 128x128 tile, 4 waves in 2x2 quadrants, 4x4 MFMA 16x16x32 tiles each.
// acc += Ahi*B1 + Alo*B1 + Ahi*B2 (missing Alo*B2 ~2^-16 relative).
// Block decode: the two column-half blocks of a row-tile are 8 ids apart -> same XCD
// under round-robin dispatch -> second A read served from that XCD's L2.
struct MJob { const float* A; const unsigned short* BThi; const unsigned short* BTlo;
              float* C; unsigned short* Cbf; const float* bias; int M; int K; int relu; };
struct MBatch { MJob j[8]; };

__global__ __launch_bounds__(256, 2) void gemm_mfma(MBatch batch)
{
    const MJob jb = batch.j[blockIdx.z];
    const int bx = blockIdx.x;
    const int rowblk = (bx >> 4) * 8 + (bx & 7);
    const int half = (bx >> 3) & 1;
    const int bm = rowblk * 128;
    if (bm >= jb.M) return;
    const int bn = half * 128;
    const int M = jb.M, K = jb.K;

    __shared__ unsigned short Ah[128 * 40];
    __shared__ unsigned short Al[128 * 40];
    __shared__ unsigned short B1[128 * 40];
    __shared__ unsigned short B2[128 * 40];

    const int tid  = threadIdx.x;
    const int wv   = tid >> 6;
    const int lane = tid & 63;
    const int qr = wv >> 1, qc = wv & 1;
    const int lm = lane & 15;
    const int lq = lane >> 4;

    accf4 acc[4][4] = {};   // [mt][nt]

    for (int k0 = 0; k0 < K; k0 += 32) {
#pragma unroll
        for (int it = 0; it < 4; ++it) {
            int slot = it * 256 + tid;
            int m  = slot >> 3;
            int kq = (slot & 7) << 2;
            float4 v = make_float4(0.f, 0.f, 0.f, 0.f);
            if (bm + m < M) v = *(const float4*)(jb.A + (size_t)(bm + m) * K + k0 + kq);
            int o = m * 40 + kq;
            unsigned short h0 = f2bf(v.x), h1 = f2bf(v.y), h2 = f2bf(v.z), h3 = f2bf(v.w);
            Ah[o + 0] = h0; Ah[o + 1] = h1; Ah[o + 2] = h2; Ah[o + 3] = h3;
            Al[o + 0] = f2bf(v.x - bf2f(h0));
            Al[o + 1] = f2bf(v.y - bf2f(h1));
            Al[o + 2] = f2bf(v.z - bf2f(h2));
            Al[o + 3] = f2bf(v.w - bf2f(h3));
        }
#pragma unroll
        for (int it = 0; it < 2; ++it) {
            int slot = it * 256 + tid;
            int n  = slot >> 2;
            int kq = (slot & 3) << 3;
            size_t go = (size_t)(bn + n) * K + k0 + kq;
            *(uint4*)&B1[n * 40 + kq] = *(const uint4*)(jb.BThi + go);
            *(uint4*)&B2[n * 40 + kq] = *(const uint4*)(jb.BTlo + go);
        }
        __syncthreads();

        bfrag8 ah[4], al[4], b1[4], b2[4];
#pragma unroll
        for (int t = 0; t < 4; ++t) {
            int am  = qr * 64 + t * 16 + lm;
            int bnn = qc * 64 + t * 16 + lm;
            ah[t] = *(const bfrag8*)&Ah[am * 40 + lq * 8];
            al[t] = *(const bfrag8*)&Al[am * 40 + lq * 8];
            b1[t] = *(const bfrag8*)&B1[bnn * 40 + lq * 8];
            b2[t] = *(const bfrag8*)&B2[bnn * 40 + lq * 8];
        }
#pragma unroll
        for (int mt = 0; mt < 4; ++mt)
#pragma unroll
            for (int nt = 0; nt < 4; ++nt) {
                acc[mt][nt] = __builtin_amdgcn_mfma_f32_16x16x32_bf16(ah[mt], b1[nt], acc[mt][nt], 0, 0, 0);
                acc[mt][nt] = __builtin_amdgcn_mfma_f32_16x16x32_bf16(al[mt], b1[nt], acc[mt][nt], 0, 0, 0);
                acc[mt][nt] = __builtin_amdgcn_mfma_f32_16x16x32_bf16(ah[mt], b2[nt], acc[mt][nt], 0, 0, 0);
            }
        __syncthreads();
    }

#pragma unroll
    for (int nt = 0; nt < 4; ++nt) {
        int col = bn + qc * 64 + nt * 16 + lm;
        float bv = jb.bias ? jb.bias[col] : 0.f;
#pragma unroll
        for (int mt = 0; mt < 4; ++mt) {
            int row0 = bm + qr * 64 + mt * 16 + lq * 4;
#pragma unroll
            for (int r = 0; r < 4; ++r) {
                int row = row0 + r;
                if (row < M) {
                    float o = acc[mt][nt][r] + bv;
                    if (jb.relu) o = fmaxf(o, 0.f);
                    if (jb.C)   jb.C[(size_t)row * 256 + col] = o;
                    if (jb.Cbf) jb.Cbf[(size_t)row * 256 + col] = f2bf(o);
                }
            }
        }
    }
}

// ---------------- effective attention-projection matrices ----------------
// weff layout: [l(2)][nt(5)][k(256)][col(32)]
__global__ __launch_bounds__(256) void fill_weff(const float* __restrict__ Wsrc,
                                                 const float* __restrict__ Wdst,
                                                 const float* __restrict__ asrc,
                                                 const float* __restrict__ adst,
                                                 float* __restrict__ weff)
{
    int idx = blockIdx.x * 256 + threadIdx.x;
    if (idx >= 81920) return;
    int col = idx & 31;
    int k   = (idx >> 5) & 255;
    int lnt = idx >> 13;
    int nt  = lnt % 5;
    int l   = lnt / 5;
    bool is_src; int t, h;
    if (nt == 0) {
        if (col < 16) { is_src = true;  t = (col >> 2) * 2;            h = col & 3; }
        else          { is_src = false; t = ((col - 16) >> 2) * 2 + 1; h = col & 3; }
    } else {
        if (col < 4)      { is_src = true;  t = 2 * nt - 1; h = col; }
        else if (col < 8) { is_src = false; t = 2 * nt - 2; h = col - 4; }
        else { weff[idx] = 0.f; return; }
    }
    const float* W = (is_src ? Wsrc : Wdst) + ((size_t)((l * 8 + t) * 256 + k)) * 256 + h * 64;
    const float* a = (is_src ? asrc : adst) + ((size_t)((l * 8 + t) * 4 + h)) * 64;
    float val = 0.f;
    for (int c = 0; c < 64; c++) val += W[c] * a[c];
    weff[idx] = val;
}

// ---------------- fold projections through L1 attn ----------------
__global__ __launch_bounds__(256) void fillEff(const float* __restrict__ Wp_ts,
                                               const float* __restrict__ bp_ts,
                                               const float* __restrict__ Wp_c,
                                               const float* __restrict__ bp_c,
                                               const float* __restrict__ weff,  // l=0 block
                                               float* __restrict__ effT,        // [64][32]
                                               float* __restrict__ biasT,       // [32]
                                               float* __restrict__ effC,        // [4][128][8]
                                               float* __restrict__ biasC)       // [4][8]
{
    int idx = blockIdx.x * 256 + threadIdx.x;
    if (idx < 2048) {
        int kk = idx >> 5, j = idx & 31;
        float s = 0.f;
        for (int k = 0; k < 256; k++) s += Wp_ts[kk * 256 + k] * weff[k * 32 + j];
        effT[idx] = s;
    } else if (idx < 2080) {
        int j = idx - 2048;
        float s = 0.f;
        for (int k = 0; k < 256; k++) s += bp_ts[k] * weff[k * 32 + j];
        biasT[j] = s;
    } else if (idx < 2080 + 4 * 1032) {
        int r = idx - 2080;
        int q = r / 1032; r -= q * 1032;
        const float* wq = weff + (q + 1) * 8192;
        if (r < 1024) {
            int kk = r >> 3, j = r & 7;
            float s = 0.f;
            for (int k = 0; k < 256; k++) s += Wp_c[(size_t)q * 32768 + kk * 256 + k] * wq[k * 32 + j];
            effC[(q * 128 + kk) * 8 + j] = s;
        } else {
            int j = r - 1024;
            float s = 0.f;
            for (int k = 0; k < 256; k++) s += bp_c[q * 256 + k] * wq[k * 32 + j];
            biasC[q * 8 + j] = s;
        }
    }
}

// attnT_L1 = ts_x @ effT + biasT
__global__ __launch_bounds__(256) void attnprojA(const float* __restrict__ ts_x,
                                                 const float* __restrict__ effT,
                                                 const float* __restrict__ biasT,
                                                 float* __restrict__ attnT)
{
    int n = blockIdx.x * 256 + threadIdx.x;
    if (n >= 50000) return;
    float acc[32];
#pragma unroll
    for (int j = 0; j < 32; j++) acc[j] = biasT[j];
    const float* xr = ts_x + (size_t)n * 64;
    for (int k = 0; k < 64; k += 4) {
        float4 xv = *(const float4*)(xr + k);
#pragma unroll
        for (int j = 0; j < 32; j++)
            acc[j] += xv.x * effT[(k + 0) * 32 + j] + xv.y * effT[(k + 1) * 32 + j]
                    + xv.z * effT[(k + 2) * 32 + j] + xv.w * effT[(k + 3) * 32 + j];
    }
#pragma unroll
    for (int j = 0; j < 32; j++) attnT[(size_t)n * 32 + j] = acc[j];
}

// attnC_L1 = emb @ effC + biasC
__global__ __launch_bounds__(256) void attnprojC1(const float* __restrict__ e0,
                                                  const float* __restrict__ e1,
                                                  const float* __restrict__ e2,
                                                  const float* __restrict__ e3,
                                                  const float* __restrict__ effC,
                                                  const float* __restrict__ biasC,
                                                  float* __restrict__ attnC)
{
    int m = blockIdx.x * 256 + threadIdx.x;
    if (m >= 34000) return;
    int q, loc;
    if (m < 1000)       { q = 0; loc = m; }
    else if (m < 21000) { q = 1; loc = m - 1000; }
    else if (m < 26000) { q = 2; loc = m - 21000; }
    else                { q = 3; loc = m - 26000; }
    const float* er = (q == 0 ? e0 : q == 1 ? e1 : q == 2 ? e2 : e3) + (size_t)loc * 128;
    const float* W = effC + q * 1024;
    float acc[8];
#pragma unroll
    for (int j = 0; j < 8; j++) acc[j] = biasC[q * 8 + j];
    for (int k = 0; k < 128; k += 4) {
        float4 xv = *(const float4*)(er + k);
#pragma unroll
        for (int j = 0; j < 8; j++)
            acc[j] += xv.x * W[(k + 0) * 8 + j] + xv.y * W[(k + 1) * 8 + j]
                    + xv.z * W[(k + 2) * 8 + j] + xv.w * W[(k + 3) * 8 + j];
    }
#pragma unroll
    for (int j = 0; j < 8; j++) attnC[(size_t)m * 8 + j] = acc[j];
}

// attnC_L2 from materialized x1 compact rows
template<int NO>
__device__ __forceinline__ void attnproj_body(const float* __restrict__ xrow,
                                              const float* __restrict__ W,
                                              float* __restrict__ out)
{
    float acc[NO];
#pragma unroll
    for (int j = 0; j < NO; j++) acc[j] = 0.f;
    for (int k = 0; k < 256; k += 4) {
        const float4 xv = *(const float4*)(xrow + k);
#pragma unroll
        for (int j = 0; j < NO; j++) {
            acc[j] += xv.x * W[(k + 0) * 32 + j] + xv.y * W[(k + 1) * 32 + j]
                    + xv.z * W[(k + 2) * 32 + j] + xv.w * W[(k + 3) * 32 + j];
        }
    }
#pragma unroll
    for (int j = 0; j < NO; j++) out[j] = acc[j];
}

__global__ __launch_bounds__(256) void attnprojC2(const float* __restrict__ x1,
                                                  const float* __restrict__ weff_l,
                                                  float* __restrict__ attnC)
{
    int m = blockIdx.x * 256 + threadIdx.x;
    if (m >= 34000) return;
    int n = 50000 + m;
    int nt = (n < 51000) ? 1 : (n < 71000) ? 2 : (n < 76000) ? 3 : 4;
    attnproj_body<8>(x1 + (size_t)n * 256, weff_l + nt * 8192, attnC + (size_t)m * 8);
}

// ---------------- CSR build ----------------
__global__ __launch_bounds__(256) void count_k(EI8 ei, int* __restrict__ cnt)
{
    int g = blockIdx.x * 256 + threadIdx.x;
    if (g >= 8 * E_N) return;
    int t = g / E_N;
    int i = g - t * E_N;
    int d = ei.p[t][E_N + i];
    atomicAdd(&cnt[c_tbase[t] + d], 1);
}

__global__ __launch_bounds__(256) void scanA(const int* __restrict__ cnt,
                                             int* __restrict__ rowptr,
                                             int* __restrict__ bsum)
{
    __shared__ int sd[256];
    int b = blockIdx.x, t = threadIdx.x;
    int base = b * 1024 + t * 4;
    int v0 = 0, v1 = 0, v2 = 0, v3 = 0;
    if (base + 0 < NDST) v0 = cnt[base + 0];
    if (base + 1 < NDST) v1 = cnt[base + 1];
    if (base + 2 < NDST) v2 = cnt[base + 2];
    if (base + 3 < NDST) v3 = cnt[base + 3];
    int s = v0 + v1 + v2 + v3;
    sd[t] = s;
    __syncthreads();
    for (int off = 1; off < 256; off <<= 1) {
        int x = 0;
        if (t >= off) x = sd[t - off];
        __syncthreads();
        if (t >= off) sd[t] += x;
        __syncthreads();
    }
    int run = sd[t] - s;
    if (t == 255) bsum[b] = sd[255];
    if (base + 0 < NDST) rowptr[base + 0] = run;          run += v0;
    if (base + 1 < NDST) rowptr[base + 1] = run;          run += v1;
    if (base + 2 < NDST) rowptr[base + 2] = run;          run += v2;
    if (base + 3 < NDST) rowptr[base + 3] = run;
}

__global__ __launch_bounds__(256) void scanB(int* __restrict__ bsum, int nb)
{
    __shared__ int sd[256];
    int t = threadIdx.x;
    int v = (t < nb) ? bsum[t] : 0;
    sd[t] = v;
    __syncthreads();
    for (int off = 1; off < 256; off <<= 1) {
        int x = 0;
        if (t >= off) x = sd[t - off];
        __syncthreads();
        if (t >= off) sd[t] += x;
        __syncthreads();
    }
    if (t < nb) bsum[t] = sd[t] - v;
}

__global__ __launch_bounds__(256) void scanC(int* __restrict__ rowptr,
                                             const int* __restrict__ bsum,
                                             int* __restrict__ cursor)
{
    int b = blockIdx.x, t = threadIdx.x;
    int off = bsum[b];
    int base = b * 1024 + t * 4;
#pragma unroll
    for (int j = 0; j < 4; j++) {
        int i = base + j;
        if (i < NDST) {
            int r = rowptr[i] + off;
            rowptr[i] = r;
            cursor[i] = r;
        }
    }
    if (b == 0 && t == 0) rowptr[NDST] = 8 * E_N;
}

__global__ __launch_bounds__(256) void place_k(EI8 ei, int* __restrict__ cursor,
                                               int* __restrict__ ssrc)
{
    int g = blockIdx.x * 256 + threadIdx.x;
    if (g >= 8 * E_N) return;
    int t = g / E_N;
    int i = g - t * E_N;
    int d = ei.p[t][E_N + i];
    int s = ei.p[t][i];
    int pos = atomicAdd(&cursor[c_tbase[t] + d], 1);
    ssrc[pos] = s;
}

// ---------------- aggregate-first ts->compact: bf16 gather, unroll-4 -----------------
__global__ __launch_bounds__(256) void aggx_k(const float* __restrict__ attnT,
                                              const float* __restrict__ attnC,
                                              const unsigned short* __restrict__ xtsbf,
                                              const int* __restrict__ rowptr,
                                              const int* __restrict__ ssrc,
                                              float* __restrict__ aggx)
{
    int w = blockIdx.x * 4 + (threadIdx.x >> 6);   // 0..33999 (grid 8500)
    int lane = threadIdx.x & 63;
    int h = lane >> 4;
    int ch = (h << 6) | ((lane & 15) << 2);
    int q, dloc;
    if (w < 1000)       { q = 0; dloc = w; }
    else if (w < 21000) { q = 1; dloc = w - 1000; }
    else if (w < 26000) { q = 2; dloc = w - 21000; }
    else                { q = 3; dloc = w - 26000; }
    const int csr4[4]  = {0, 51000, 121000, 176000};
    const int soff4[4] = {0, 4, 8, 12};
    int soff = soff4[q];
    int r0 = rowptr[csr4[q] + dloc], r1 = rowptr[csr4[q] + dloc + 1];
    float ed = attnC[(size_t)w * 8 + 4 + h];
    float den = 0.f, sx = 0.f, sy = 0.f, sz = 0.f, sw = 0.f;
    int e = r0;
    for (; e + 4 <= r1; e += 4) {
        int sA = ssrc[e], sB = ssrc[e + 1], sC = ssrc[e + 2], sD = ssrc[e + 3];
        float eA = attnT[(size_t)sA * 32 + soff + h];
        float eB = attnT[(size_t)sB * 32 + soff + h];
        float eC = attnT[(size_t)sC * 32 + soff + h];
        float eD = attnT[(size_t)sD * 32 + soff + h];
        ushort4 rA = *(const ushort4*)(xtsbf + (size_t)sA * 256 + ch);
        ushort4 rB = *(const ushort4*)(xtsbf + (size_t)sB * 256 + ch);
        ushort4 rC = *(const ushort4*)(xtsbf + (size_t)sC * 256 + ch);
        ushort4 rD = *(const ushort4*)(xtsbf + (size_t)sD * 256 + ch);
        float xA = __expf(lrelu(eA + ed));
        float xB = __expf(lrelu(eB + ed));
        float xC = __expf(lrelu(eC + ed));
        float xD = __expf(lrelu(eD + ed));
        den += (xA + xB) + (xC + xD);
        sx += xA * bf2f(rA.x) + xB * bf2f(rB.x) + xC * bf2f(rC.x) + xD * bf2f(rD.x);
        sy += xA * bf2f(rA.y) + xB * bf2f(rB.y) + xC * bf2f(rC.y) + xD * bf2f(rD.y);
        sz += xA * bf2f(rA.z) + xB * bf2f(rB.z) + xC * bf2f(rC.z) + xD * bf2f(rD.z);
        sw += xA * bf2f(rA.w) + xB * bf2f(rB.w) + xC * bf2f(rC.w) + xD * bf2f(rD.w);
    }
    for (; e < r1; e++) {
        int s = ssrc[e];
        float es = attnT[(size_t)s * 32 + soff + h];
        float ex = __expf(lrelu(es + ed));
        den += ex;
        ushort4 rv = *(const ushort4*)(xtsbf + (size_t)s * 256 + ch);
        sx += ex * bf2f(rv.x); sy += ex * bf2f(rv.y);
        sz += ex * bf2f(rv.z); sw += ex * bf2f(rv.w);
    }
    float inv = 1.f / (den + 1e-16f);
    float4 o; o.x = sx * inv; o.y = sy * inv; o.z = sz * inv; o.w = sw * inv;
    *(float4*)(aggx + (size_t)w * 256 + ch) = o;
}

// ---------------- fused compact->ts aggregation core (sequential-q, unroll-2) --------
__device__ __forceinline__ float4 agg_ts_core(const float* __restrict__ attnT,
                                              const float* __restrict__ attnC,
                                              const unsigned short* __restrict__ hscbf,
                                              const int* __restrict__ rowptr,
                                              const int* __restrict__ ssrc,
                                              const float* __restrict__ bconv_l,
                                              int d, int h, int ch)
{
    const int co4[4]   = {0, 1000, 21000, 26000};
    const int tb4[4]   = {1000, 71000, 126000, 184000};
    const int doff4[4] = {16, 20, 24, 28};
    const int bo4[4]   = {256, 768, 1280, 1792};
    float ax = 0.f, ay = 0.f, az = 0.f, aw = 0.f;
#pragma unroll
    for (int q = 0; q < 4; q++) {
        int r0 = rowptr[tb4[q] + d], r1 = rowptr[tb4[q] + d + 1];
        float ed = attnT[(size_t)d * 32 + doff4[q] + h];
        float den = 0.f, sx = 0.f, sy = 0.f, sz = 0.f, sw = 0.f;
        int e = r0;
        for (; e + 2 <= r1; e += 2) {
            int sA = ssrc[e], sB = ssrc[e + 1];
            float eA = attnC[(size_t)(co4[q] + sA) * 8 + h];
            float eB = attnC[(size_t)(co4[q] + sB) * 8 + h];
            ushort4 rA = *(const ushort4*)(hscbf + (size_t)(co4[q] + sA) * 256 + ch);
            ushort4 rB = *(const ushort4*)(hscbf + (size_t)(co4[q] + sB) * 256 + ch);
            float xA = __expf(lrelu(eA + ed));
            float xB = __expf(lrelu(eB + ed));
            den += xA + xB;
            sx += xA * bf2f(rA.x) + xB * bf2f(rB.x);
            sy += xA * bf2f(rA.y) + xB * bf2f(rB.y);
            sz += xA * bf2f(rA.z) + xB * bf2f(rB.z);
            sw += xA * bf2f(rA.w) + xB * bf2f(rB.w);
        }
        if (e < r1) {
            int s = ssrc[e];
            float es = attnC[(size_t)(co4[q] + s) * 8 + h];
            float ex = __expf(lrelu(es + ed));
            den += ex;
            ushort4 hv = *(const ushort4*)(hscbf + (size_t)(co4[q] + s) * 256 + ch);
            sx += ex * bf2f(hv.x); sy += ex * bf2f(hv.y);
            sz += ex * bf2f(hv.z); sw += ex * bf2f(hv.w);
        }
        const float* b = bconv_l + bo4[q] + ch;
        float inv = 1.f / (den + 1e-16f);
        ax += b[0] + sx * inv; ay += b[1] + sy * inv;
        az += b[2] + sz * inv; aw += b[3] + sw * inv;
    }
    float4 o;
    o.x = fmaxf(ax, 0.f); o.y = fmaxf(ay, 0.f);
    o.z = fmaxf(az, 0.f); o.w = fmaxf(aw, 0.f);
    return o;
}

// L1: compute row, fold attnT_L2 (cols 16..31) in-place; x1 ts rows never materialized.
// Fold uses all 64 lanes: j = lane&15, seg = lane>>4, 64 MACs + butterfly reduce.
__global__ __launch_bounds__(256) void agg_ts_fold(float* __restrict__ attnT,   // in(L1)/out(L2)
                                                   const float* __restrict__ attnC,
                                                   const unsigned short* __restrict__ hscbf,
                                                   const int* __restrict__ rowptr,
                                                   const int* __restrict__ ssrc,
                                                   const float* __restrict__ bconv_l,
                                                   const float* __restrict__ weff2)  // l=1,nt=0 [256][32]
{
    int wv = threadIdx.x >> 6;
    int d = blockIdx.x * 4 + wv;                  // grid 12500
    int lane = threadIdx.x & 63;
    int h = lane >> 4;
    int ch = (h << 6) | ((lane & 15) << 2);
    float4 o = agg_ts_core(attnT, attnC, hscbf, rowptr, ssrc, bconv_l, d, h, ch);
    __shared__ float rowbuf[4][256];
    rowbuf[wv][ch + 0] = o.x; rowbuf[wv][ch + 1] = o.y;
    rowbuf[wv][ch + 2] = o.z; rowbuf[wv][ch + 3] = o.w;
    __syncthreads();
    // fold: all 64 lanes. lane = seg*16 + j ; each lane does 64 MACs over its segment.
    {
        int j = lane & 15, seg = lane >> 4;
        const float* rb = rowbuf[wv] + seg * 64;
        const float* w2 = weff2 + (seg * 64) * 32 + 16 + j;
        float s = 0.f;
#pragma unroll 8
        for (int c = 0; c < 64; c++) s += rb[c] * w2[c * 32];
        s += __shfl_xor(s, 16);
        s += __shfl_xor(s, 32);
        if (lane < 16) attnT[(size_t)d * 32 + 16 + lane] = s;
    }
}

// L2: block-reduce 4 node rows -> one 256-float partial per block (no x write)
__global__ __launch_bounds__(256) void agg_ts_pool(const float* __restrict__ attnT,
                                                   const float* __restrict__ attnC,
                                                   const unsigned short* __restrict__ hscbf,
                                                   const int* __restrict__ rowptr,
                                                   const int* __restrict__ ssrc,
                                                   const float* __restrict__ bconv_l,
                                                   float* __restrict__ part)
{
    int d = blockIdx.x * 4 + (threadIdx.x >> 6);   // grid 12500
    int lane = threadIdx.x & 63;
    int h = lane >> 4;
    int ch = (h << 6) | ((lane & 15) << 2);
    float4 o = agg_ts_core(attnT, attnC, hscbf, rowptr, ssrc, bconv_l, d, h, ch);
    __shared__ float4 red4[256];
    red4[threadIdx.x] = o;
    __syncthreads();
    if (threadIdx.x < 64) {
        float4 a = red4[threadIdx.x], b = red4[threadIdx.x + 64];
        float4 c = red4[threadIdx.x + 128], dd = red4[threadIdx.x + 192];
        float4 s;
        s.x = (a.x + b.x) + (c.x + dd.x);
        s.y = (a.y + b.y) + (c.y + dd.y);
        s.z = (a.z + b.z) + (c.z + dd.z);
        s.w = (a.w + b.w) + (c.w + dd.w);
        int cch = ((threadIdx.x >> 4) << 6) | ((threadIdx.x & 15) << 2);
        *(float4*)(part + (size_t)blockIdx.x * 256 + cch) = s;
    }
}

// reduce partials: gsum[c] = sum over 12500 block rows
__global__ __launch_bounds__(256) void colsum_part(const float* __restrict__ part,
                                                   float* __restrict__ gsum)
{
    int c = threadIdx.x;
    float s = 0.f;
    for (int r = blockIdx.x; r < 12500; r += gridDim.x) s += part[(size_t)r * 256 + c];
    atomAddF(gsum + c, s);
}

// ---------------- head ----------------
__global__ __launch_bounds__(128) void head_k(const float* __restrict__ gsum,
                                              const float* __restrict__ Wc1,
                                              const float* __restrict__ bc1,
                                              const float* __restrict__ Wc2,
                                              const float* __restrict__ bc2,
                                              float* __restrict__ out)
{
    __shared__ float g[256];
    __shared__ float red[128];
    int t = threadIdx.x;
    g[t] = gsum[t] * (1.f / 50000.f);
    g[t + 128] = gsum[t + 128] * (1.f / 50000.f);
    __syncthreads();
    float acc = bc1[t];
    for (int k = 0; k < 256; k++) acc += g[k] * Wc1[k * 128 + t];
    red[t] = fmaxf(acc, 0.f) * Wc2[t];
    __syncthreads();
    for (int sft = 64; sft > 0; sft >>= 1) {
        if (t < sft) red[t] += red[t + sft];
        __syncthreads();
    }
    if (t == 0) out[0] = red[0] + bc2[0];
}

extern "C" void kernel_launch(void* const* d_in, const int* in_sizes, int n_in,
                              void* d_out, int out_size, void* d_ws, size_t ws_size,
                              hipStream_t stream)
{
    const float* ts_x   = (const float*)d_in[0];
    const float* emb[4] = {(const float*)d_in[1], (const float*)d_in[2],
                           (const float*)d_in[3], (const float*)d_in[4]};
    const float* Wp_ts  = (const float*)d_in[5];
    const float* bp_ts  = (const float*)d_in[6];
    const float* Wp_c   = (const float*)d_in[7];
    const float* bp_c   = (const float*)d_in[8];
    const float* Wsrc   = (const float*)d_in[9];
    const float* Wdst   = (const float*)d_in[10];
    const float* asrc   = (const float*)d_in[11];
    const float* adst   = (const float*)d_in[12];
    const float* bconv  = (const float*)d_in[13];
    const float* Wc1    = (const float*)d_in[14];
    const float* bc1    = (const float*)d_in[15];
    const float* Wc2    = (const float*)d_in[16];
    const float* bc2    = (const float*)d_in[17];
    EI8 ei;
    for (int t = 0; t < 8; t++) ei.p[t] = (const int*)d_in[18 + t];

    // workspace layout (float units)
    float* x0    = (float*)d_ws;           // 21,504,000 (only compact region used)
    float* x1    = x0    + 21504000;       // 21,504,000 (ts region = aggx; compact region = L2 input)
    float* attnT = x1    + 21504000;       // 1,600,000
    float* attnC = attnT + 1600000;        // 272,000
    float* weff  = attnC + 272000;         // 81,920
    float* gsum  = weff  + 81920;          // 256
    float* effT  = gsum  + 256;            // 2,048
    float* biasT = effT  + 2048;           // 32
    float* effC  = biasT + 32;             // 4,096
    float* biasC = effC  + 4096;           // 32
    int* rowptr  = (int*)(biasC + 32);     // 234,004
    int* bsum    = rowptr + 234004;        // 256
    int* ssrc    = bsum + 256;             // 800,000
    unsigned short* xtsbf = (unsigned short*)(ssrc + 800000);   // 12,800,000 us
    unsigned short* hscbf = xtsbf + 12800000;                   //  8,704,000 us
    unsigned short* btp   = hscbf + 8704000;                    //  1,867,776 us
    int* cursor  = (int*)hscbf;            // alias: CSR build finishes before hscbf used
    float* aggx  = x1;                     // alias ts region of x1 (rows 0..33999)
    float* part  = x0;                     // alias: x0 ts region unused; compact reads done before pool

    unsigned short* bt_ts_h = btp;
    unsigned short* bt_ts_l = bt_ts_h + 16384;
    unsigned short* bt_c_h[4], *bt_c_l[4];
    {
        unsigned short* p = bt_ts_l + 16384;
        for (int q = 0; q < 4; q++) { bt_c_h[q] = p; p += 32768; bt_c_l[q] = p; p += 32768; }
    }
    unsigned short* bt_w = bt_ts_l + 16384 + 8 * 32768;
    auto wpan_h = [&](int l, int t) { return bt_w + (size_t)((l == 0 ? t : 8 + t / 2) * 2) * 65536; };
    auto wpan_l = [&](int l, int t) { return wpan_h(l, t) + 65536; };

    // ---- CSR build ----
    hipMemsetAsync(cursor, 0, NDST * sizeof(int), stream);
    count_k<<<3125, 256, 0, stream>>>(ei, cursor);
    scanA<<<229, 256, 0, stream>>>(cursor, rowptr, bsum);
    scanB<<<1, 256, 0, stream>>>(bsum, 229);
    scanC<<<229, 256, 0, stream>>>(rowptr, bsum, cursor);
    place_k<<<3125, 256, 0, stream>>>(ei, cursor, ssrc);

    // ---- weight pre-split ----
    {
        BTBatch b = {};
        int zi = 0;
        b.j[zi++] = {Wp_ts, bt_ts_h, bt_ts_l, 64, 6};
        for (int q = 0; q < 4; q++)
            b.j[zi++] = {Wp_c + q * 32768, bt_c_h[q], bt_c_l[q], 128, 7};
        for (int t = 0; t < 8; t++)
            b.j[zi++] = {Wsrc + (size_t)(0 * 8 + t) * 65536, wpan_h(0, t), wpan_l(0, t), 256, 8};
        for (int t = 1; t < 8; t += 2)
            b.j[zi++] = {Wsrc + (size_t)(1 * 8 + t) * 65536, wpan_h(1, t), wpan_l(1, t), 256, 8};
        makeBT<<<dim3(256, 1, 17), 256, 0, stream>>>(b);
    }

    fill_weff<<<320, 256, 0, stream>>>(Wsrc, Wdst, asrc, adst, weff);
    fillEff<<<25, 256, 0, stream>>>(Wp_ts, bp_ts, Wp_c, bp_c, weff, effT, biasT, effC, biasC);

    // ---- L1 attn logits directly from inputs (folded) ----
    attnprojA<<<196, 256, 0, stream>>>(ts_x, effT, biasT, attnT);
    attnprojC1<<<133, 256, 0, stream>>>(emb[0], emb[1], emb[2], emb[3], effC, biasC, attnC);

    static const int Nd4[4]    = {1000, 20000, 5000, 8000};
    static const int co4[4]    = {0, 1000, 21000, 26000};
    static const int dbase4[4] = {50000, 51000, 71000, 76000};
    static const int tsrc[4]   = {1, 3, 5, 7};
    static const int tdst[4]   = {0, 2, 4, 6};

    // ---- input projections: ts -> bf16 shadow only; compact -> x0 fp32 ----
    {
        MBatch b = {};
        b.j[0] = {ts_x, bt_ts_h, bt_ts_l, nullptr, xtsbf, bp_ts, 50000, 64, 0};
        for (int q = 0; q < 4; q++)
            b.j[1 + q] = {emb[q], bt_c_h[q], bt_c_l[q], x0 + (size_t)dbase4[q] * 256,
                          nullptr, bp_c + q * 256, Nd4[q], 128, 0};
        gemm_mfma<<<dim3(784, 1, 5), 256, 0, stream>>>(b);
    }

    // ---- layer 1 ----
    aggx_k<<<8500, 256, 0, stream>>>(attnT, attnC, xtsbf, rowptr, ssrc, aggx);
    {
        MBatch b = {};
        for (int q = 0; q < 4; q++)
            b.j[q] = {x0 + (size_t)dbase4[q] * 256, wpan_h(0, tsrc[q]), wpan_l(0, tsrc[q]),
                      nullptr, hscbf + (size_t)co4[q] * 256, nullptr, Nd4[q], 256, 0};
        for (int q = 0; q < 4; q++)
            b.j[4 + q] = {aggx + (size_t)co4[q] * 256, wpan_h(0, tdst[q]), wpan_l(0, tdst[q]),
                          x1 + (size_t)dbase4[q] * 256, nullptr, bconv + tdst[q] * 256, Nd4[q], 256, 1};
        gemm_mfma<<<dim3(320, 1, 8), 256, 0, stream>>>(b);
    }
    // L1 aggregation + fold attnT_L2 (in-place); x1 ts rows never written
    agg_ts_fold<<<12500, 256, 0, stream>>>(attnT, attnC, hscbf, rowptr, ssrc, bconv, weff + 40960);

    // ---- layer 2 ----
    attnprojC2<<<133, 256, 0, stream>>>(x1, weff + 40960, attnC);
    {
        MBatch b = {};
        for (int q = 0; q < 4; q++)
            b.j[q] = {x1 + (size_t)dbase4[q] * 256, wpan_h(1, tsrc[q]), wpan_l(1, tsrc[q]),
                      nullptr, hscbf + (size_t)co4[q] * 256, nullptr, Nd4[q], 256, 0};
        gemm_mfma<<<dim3(320, 1, 4), 256, 0, stream>>>(b);
    }
    agg_ts_pool<<<12500, 256, 0, stream>>>(attnT, attnC, hscbf, rowptr, ssrc, bconv + 2048, part);
    hipMemsetAsync(gsum, 0, 256 * sizeof(float), stream);
    colsum_part<<<256, 256, 0, stream>>>(part, gsum);

    head_k<<<1, 128, 0, stream>>>(gsum, Wc1, bc1, Wc2, bc2, (float*)d_out);
}